// Round 10
// baseline (133.166 us; speedup 1.0000x reference)
//
#include <hip/hip_runtime.h>

// CrumbReconstructor R13: halve LDS-broadcast traffic per CU (TPK 2->4 at
// constant waves/SIMD>=3), keep R12's proven window/group-min codegen,
// move all divergent reads (resolve + gather) off the LDS pipe to global.
//
// R12 post-mortem: kernel is LDS-RETURN-BANDWIDTH bound. Broadcast
// ds_read_b128 delivers 16B x 64 lanes = 1024B (m134: ~85 B/cy/CU): R12 =
// 590KB/wave x 24.5 waves/CU / 85B/cy = 70.8us (measured 69.5); R3 = 78
// (measured 72). Instruction cuts can't help until LDS bytes/CU drop.
//
// Changes: BLOCK=64 (1-wave blocks), TPK=4, grid=3136 = 12.25 blocks/CU
// (6% imbalance, R6-proven shape; 3.06 waves/SIMD). LDS/CU -> 35us, VALU
// -> ~31us: pipes balanced. WIN=4 flat windows (9 broadcast LDS issues /
// 4 rows). Resolve + gather read the 8KB L1-resident codebook from GLOBAL
// (kills R12's 3.2M resolve-phase bank conflicts).
//
// Exactness (absmax must stay 0.0):
//  - distance d: identical fp32 sequence (mul, 7x fmaf, fmaf(dot,-2,knorm),
//    + rn) everywhere; LDS copies are verbatim, so scan d == resolve d;
//  - group-min value is order-independent (no NaN/inf possible); strict
//    (gmin < best) keeps the FIRST group attaining the global min;
//  - resolve recomputes the 4 group distances bit-identically (norms
//    recomputed from the same bytes with the same op tree) and takes the
//    first j with d == best -> exact reference first-index argmin.

#define LBLK 8          // memblock length
#define NROW 256        // codebook rows
#define BLOCK 64        // 1 wave per block
#define TPK 4           // keys per thread
#define WIN 4           // rows per window / argmin group

__global__ __launch_bounds__(BLOCK, 3) void crumb_kernel(
    const float* __restrict__ x,
    const float* __restrict__ mem,
    float* __restrict__ out,
    int nblocks)
{
    __shared__ float s_mem[NROW * LBLK];            // 8 KB, rows contiguous
    __shared__ __align__(16) float s_norm[NROW];    // 1 KB, b128 window reads

    const int lane = threadIdx.x;

    // --- stage codebook: 4 rows per thread (reads are L2/L3-absorbed) ---
    {
        const float4* g = (const float4*)mem;
        #pragma unroll
        for (int c = 0; c < 4; ++c) {
            const int rr = c * 64 + lane;
            float4 a = g[rr * 2 + 0];
            float4 b = g[rr * 2 + 1];
            ((float4*)s_mem)[rr * 2 + 0] = a;
            ((float4*)s_mem)[rr * 2 + 1] = b;
            float q0 = a.x * a.x, q1 = a.y * a.y, q2 = a.z * a.z, q3 = a.w * a.w;
            float q4 = b.x * b.x, q5 = b.y * b.y, q6 = b.z * b.z, q7 = b.w * b.w;
            s_norm[rr] = ((q0 + q1) + (q2 + q3)) + ((q4 + q5) + (q6 + q7));
        }
    }
    __syncthreads();

    // --- load 4 keys per thread (coalesced per wave) ---
    const long base = (long)blockIdx.x * (BLOCK * TPK) + lane;

    float k[TPK][LBLK];
    float knorm[TPK];

    #pragma unroll
    for (int t = 0; t < TPK; ++t) {
        long b0 = base + (long)t * 64;
        long kbt = (b0 < (long)nblocks) ? b0 : 0;
        const float4* g = (const float4*)(x + kbt * LBLK);
        float4 a = g[0], b = g[1];
        k[t][0] = a.x; k[t][1] = a.y; k[t][2] = a.z; k[t][3] = a.w;
        k[t][4] = b.x; k[t][5] = b.y; k[t][6] = b.z; k[t][7] = b.w;
        float q0 = a.x * a.x, q1 = a.y * a.y, q2 = a.z * a.z, q3 = a.w * a.w;
        float q4 = b.x * b.x, q5 = b.y * b.y, q6 = b.z * b.z, q7 = b.w * b.w;
        knorm[t] = ((q0 + q1) + (q2 + q3)) + ((q4 + q5) + (q6 + q7));
    }

    float best[TPK];
    int   gbs[TPK];
    #pragma unroll
    for (int t = 0; t < TPK; ++t) { best[t] = 3.4e38f; gbs[t] = 0; }

    const float4* sm4 = (const float4*)s_mem;

    // the exact reference distance chain (bit-identical everywhere)
#define DIST(T, RA, RB, RN, DST)                                        \
    {                                                                   \
        float dot = k[(T)][0] * (RA).x;                                 \
        dot = fmaf(k[(T)][1], (RA).y, dot);                             \
        dot = fmaf(k[(T)][2], (RA).z, dot);                             \
        dot = fmaf(k[(T)][3], (RA).w, dot);                             \
        dot = fmaf(k[(T)][4], (RB).x, dot);                             \
        dot = fmaf(k[(T)][5], (RB).y, dot);                             \
        dot = fmaf(k[(T)][6], (RB).z, dot);                             \
        dot = fmaf(k[(T)][7], (RB).w, dot);                             \
        (DST) = fmaf(dot, -2.0f, knorm[(T)]) + (RN);                    \
    }

    // --- scan: 4-row windows, flat broadcast loads, group-4 argmin ---
    #pragma unroll 1
    for (int r = 0; r < NROW; r += WIN) {
        float4 A0 = sm4[(r + 0) * 2 + 0], B0 = sm4[(r + 0) * 2 + 1];
        float4 A1 = sm4[(r + 1) * 2 + 0], B1 = sm4[(r + 1) * 2 + 1];
        float4 A2 = sm4[(r + 2) * 2 + 0], B2 = sm4[(r + 2) * 2 + 1];
        float4 A3 = sm4[(r + 3) * 2 + 0], B3 = sm4[(r + 3) * 2 + 1];
        float4 N  = *(const float4*)&s_norm[r];

        #pragma unroll
        for (int t = 0; t < TPK; ++t) {
            float d0, d1, d2, d3;
            DIST(t, A0, B0, N.x, d0);
            DIST(t, A1, B1, N.y, d1);
            DIST(t, A2, B2, N.z, d2);
            DIST(t, A3, B3, N.w, d3);
            // group min (order-independent value; all inputs finite)
            float gm = fminf(fminf(d0, d1), fminf(d2, d3));
            // strict < : FIRST group attaining the global min wins
            if (gm < best[t]) { best[t] = gm; gbs[t] = r; }
        }
    }

    // --- resolve + store: recompute winning group from GLOBAL (L1-hot),
    //     take first d == best (lowest index), write its row ---
    #pragma unroll
    for (int t = 0; t < TPK; ++t) {
        long b0 = base + (long)t * 64;
        if (b0 < (long)nblocks) {
            const int gb = gbs[t];
            float4 wa = ((const float4*)(mem + (long)gb * LBLK))[0];
            float4 wb = ((const float4*)(mem + (long)gb * LBLK))[1];
            bool found = false;
            #pragma unroll
            for (int j = 0; j < WIN; ++j) {
                const float4* g = (const float4*)(mem + (long)(gb + j) * LBLK);
                float4 a = g[0], b = g[1];
                // norm recomputed from the same bytes with the same op tree
                float q0 = a.x * a.x, q1 = a.y * a.y, q2 = a.z * a.z, q3 = a.w * a.w;
                float q4 = b.x * b.x, q5 = b.y * b.y, q6 = b.z * b.z, q7 = b.w * b.w;
                float nn = ((q0 + q1) + (q2 + q3)) + ((q4 + q5) + (q6 + q7));
                float d;
                DIST(t, a, b, nn, d);
                bool hit = (d == best[t]) && !found;
                if (hit) { wa = a; wb = b; }
                found = found || (d == best[t]);
            }
            float4* o = (float4*)(out + b0 * LBLK);
            o[0] = wa;
            o[1] = wb;
        }
    }
#undef DIST
}

extern "C" void kernel_launch(void* const* d_in, const int* in_sizes, int n_in,
                              void* d_out, int out_size, void* d_ws, size_t ws_size,
                              hipStream_t stream) {
    const float* x   = (const float*)d_in[0];
    const float* mem = (const float*)d_in[1];
    float* out = (float*)d_out;

    int n = in_sizes[0];            // total x elements
    int nblocks = n / LBLK;         // key-blocks (802816 for std shape)
    int grid = (nblocks + BLOCK * TPK - 1) / (BLOCK * TPK);   // 3136

    hipLaunchKernelGGL(crumb_kernel, dim3(grid), dim3(BLOCK), 0, stream,
                       x, mem, out, nblocks);
}

// Round 11
// 131.586 us; speedup vs baseline: 1.0120x; 1.0120x over previous
//
#include <hip/hip_runtime.h>

// CrumbReconstructor R14: the untested middle of the LDS-vs-TLP tradeoff.
//
// Two-rail model (fits R3..R13 quantitatively):
//   LDS-broadcast return ~85 B/cy/CU, delivered bytes = 2304 B/row/wave
//     -> LDS time/CU = waves/CU * 590KB / 85 B/cy  (TPK-inverse)
//   VALU issue ~32-34us (fixed total work)
//   overlap(max) at 6.1 waves/SIMD (R12: max(70.8,28)=70.8 ~ 69.5 meas);
//   serialization(sum) at 3.06 waves/SIMD (R13: 35.4+32=67 ~ 72 meas).
// TPK=3: LDS 47us, VALU 32us, 4.08 waves/SIMD. If overlap holds at 4/SIMD
// -> 47-55us; if not -> ~79 and R12 (69.5) is the practical floor.
//
// vs R13, ONLY these change: TPK 4->3, grid 3136->4182 (16.34 blocks/CU,
// 4% stretch), __launch_bounds__(64,5) (VGPR<=102 so 5 waves/SIMD fit).
// Scan/resolve structure and math bit-identical (absmax must stay 0.0).

#define LBLK 8          // memblock length
#define NROW 256        // codebook rows
#define BLOCK 64        // 1 wave per block
#define TPK 3           // keys per thread
#define WIN 4           // rows per window / argmin group

__global__ __launch_bounds__(BLOCK, 5) void crumb_kernel(
    const float* __restrict__ x,
    const float* __restrict__ mem,
    float* __restrict__ out,
    int nblocks)
{
    __shared__ float s_mem[NROW * LBLK];            // 8 KB, rows contiguous
    __shared__ __align__(16) float s_norm[NROW];    // 1 KB, b128 window reads

    const int lane = threadIdx.x;

    // --- stage codebook: 4 rows per thread (reads are L2/L3-absorbed) ---
    {
        const float4* g = (const float4*)mem;
        #pragma unroll
        for (int c = 0; c < 4; ++c) {
            const int rr = c * 64 + lane;
            float4 a = g[rr * 2 + 0];
            float4 b = g[rr * 2 + 1];
            ((float4*)s_mem)[rr * 2 + 0] = a;
            ((float4*)s_mem)[rr * 2 + 1] = b;
            float q0 = a.x * a.x, q1 = a.y * a.y, q2 = a.z * a.z, q3 = a.w * a.w;
            float q4 = b.x * b.x, q5 = b.y * b.y, q6 = b.z * b.z, q7 = b.w * b.w;
            s_norm[rr] = ((q0 + q1) + (q2 + q3)) + ((q4 + q5) + (q6 + q7));
        }
    }
    __syncthreads();

    // --- load 3 keys per thread (coalesced per wave) ---
    const long base = (long)blockIdx.x * (BLOCK * TPK) + lane;

    float k[TPK][LBLK];
    float knorm[TPK];

    #pragma unroll
    for (int t = 0; t < TPK; ++t) {
        long b0 = base + (long)t * 64;
        long kbt = (b0 < (long)nblocks) ? b0 : 0;
        const float4* g = (const float4*)(x + kbt * LBLK);
        float4 a = g[0], b = g[1];
        k[t][0] = a.x; k[t][1] = a.y; k[t][2] = a.z; k[t][3] = a.w;
        k[t][4] = b.x; k[t][5] = b.y; k[t][6] = b.z; k[t][7] = b.w;
        float q0 = a.x * a.x, q1 = a.y * a.y, q2 = a.z * a.z, q3 = a.w * a.w;
        float q4 = b.x * b.x, q5 = b.y * b.y, q6 = b.z * b.z, q7 = b.w * b.w;
        knorm[t] = ((q0 + q1) + (q2 + q3)) + ((q4 + q5) + (q6 + q7));
    }

    float best[TPK];
    int   gbs[TPK];
    #pragma unroll
    for (int t = 0; t < TPK; ++t) { best[t] = 3.4e38f; gbs[t] = 0; }

    const float4* sm4 = (const float4*)s_mem;

    // the exact reference distance chain (bit-identical everywhere)
#define DIST(T, RA, RB, RN, DST)                                        \
    {                                                                   \
        float dot = k[(T)][0] * (RA).x;                                 \
        dot = fmaf(k[(T)][1], (RA).y, dot);                             \
        dot = fmaf(k[(T)][2], (RA).z, dot);                             \
        dot = fmaf(k[(T)][3], (RA).w, dot);                             \
        dot = fmaf(k[(T)][4], (RB).x, dot);                             \
        dot = fmaf(k[(T)][5], (RB).y, dot);                             \
        dot = fmaf(k[(T)][6], (RB).z, dot);                             \
        dot = fmaf(k[(T)][7], (RB).w, dot);                             \
        (DST) = fmaf(dot, -2.0f, knorm[(T)]) + (RN);                    \
    }

    // --- scan: 4-row windows, flat broadcast loads, group-4 argmin ---
    #pragma unroll 1
    for (int r = 0; r < NROW; r += WIN) {
        float4 A0 = sm4[(r + 0) * 2 + 0], B0 = sm4[(r + 0) * 2 + 1];
        float4 A1 = sm4[(r + 1) * 2 + 0], B1 = sm4[(r + 1) * 2 + 1];
        float4 A2 = sm4[(r + 2) * 2 + 0], B2 = sm4[(r + 2) * 2 + 1];
        float4 A3 = sm4[(r + 3) * 2 + 0], B3 = sm4[(r + 3) * 2 + 1];
        float4 N  = *(const float4*)&s_norm[r];

        #pragma unroll
        for (int t = 0; t < TPK; ++t) {
            float d0, d1, d2, d3;
            DIST(t, A0, B0, N.x, d0);
            DIST(t, A1, B1, N.y, d1);
            DIST(t, A2, B2, N.z, d2);
            DIST(t, A3, B3, N.w, d3);
            // group min (order-independent value; all inputs finite)
            float gm = fminf(fminf(d0, d1), fminf(d2, d3));
            // strict < : FIRST group attaining the global min wins
            if (gm < best[t]) { best[t] = gm; gbs[t] = r; }
        }
    }

    // --- resolve + store: recompute winning group from GLOBAL (L1-hot),
    //     take first d == best (lowest index), write its row ---
    #pragma unroll
    for (int t = 0; t < TPK; ++t) {
        long b0 = base + (long)t * 64;
        if (b0 < (long)nblocks) {
            const int gb = gbs[t];
            float4 wa = ((const float4*)(mem + (long)gb * LBLK))[0];
            float4 wb = ((const float4*)(mem + (long)gb * LBLK))[1];
            bool found = false;
            #pragma unroll
            for (int j = 0; j < WIN; ++j) {
                const float4* g = (const float4*)(mem + (long)(gb + j) * LBLK);
                float4 a = g[0], b = g[1];
                // norm recomputed from the same bytes with the same op tree
                float q0 = a.x * a.x, q1 = a.y * a.y, q2 = a.z * a.z, q3 = a.w * a.w;
                float q4 = b.x * b.x, q5 = b.y * b.y, q6 = b.z * b.z, q7 = b.w * b.w;
                float nn = ((q0 + q1) + (q2 + q3)) + ((q4 + q5) + (q6 + q7));
                float d;
                DIST(t, a, b, nn, d);
                bool hit = (d == best[t]) && !found;
                if (hit) { wa = a; wb = b; }
                found = found || (d == best[t]);
            }
            float4* o = (float4*)(out + b0 * LBLK);
            o[0] = wa;
            o[1] = wb;
        }
    }
#undef DIST
}

extern "C" void kernel_launch(void* const* d_in, const int* in_sizes, int n_in,
                              void* d_out, int out_size, void* d_ws, size_t ws_size,
                              hipStream_t stream) {
    const float* x   = (const float*)d_in[0];
    const float* mem = (const float*)d_in[1];
    float* out = (float*)d_out;

    int n = in_sizes[0];            // total x elements
    int nblocks = n / LBLK;         // key-blocks (802816 for std shape)
    int grid = (nblocks + BLOCK * TPK - 1) / (BLOCK * TPK);   // 4182

    hipLaunchKernelGGL(crumb_kernel, dim3(grid), dim3(BLOCK), 0, stream,
                       x, mem, out, nblocks);
}